// Round 1
// baseline (1199.623 us; speedup 1.0000x reference)
//
#include <hip/hip_runtime.h>
#include <stdint.h>

#define COLS 16384
#define TPB 1024
#define NWAVES 16               // 16 waves per block (one block per row)
#define EPT 16                  // elements per thread
#define F4PT 4                  // float4 per thread
#define KCAP 64                 // supports k <= 64 (harness: k == 64)

// Order-preserving float -> u32 key map (monotone bijection over non-NaN).
__device__ __forceinline__ unsigned f2k(unsigned u) {
    return (u & 0x80000000u) ? ~u : (u | 0x80000000u);
}
// Exact inverse of f2k (bit-exact float reconstruction).
__device__ __forceinline__ unsigned k2f_bits(unsigned key) {
    return (key & 0x80000000u) ? (key ^ 0x80000000u) : ~key;
}
// Scalar popcount of a ballot mask: stays entirely in the SALU pipe.
__device__ __forceinline__ unsigned sbcnt(unsigned long long m) {
    unsigned c;
    asm("s_bcnt1_i32_b64 %0, %1" : "=s"(c) : "s"(m) : "scc");
    return c;
}
// Rank of this lane among set bits below it (v_mbcnt pair).
__device__ __forceinline__ unsigned rank_lt(unsigned long long m) {
    unsigned r = __builtin_amdgcn_mbcnt_lo((unsigned)m, 0u);
    return __builtin_amdgcn_mbcnt_hi((unsigned)(m >> 32), r);
}

__global__ __launch_bounds__(TPB, 8) void topk_row_kernel(
        const float* __restrict__ x,
        const int* __restrict__ kptr,
        float* __restrict__ out) {
    const int tid  = threadIdx.x;
    const int wid  = tid >> 6;
    const int lane = tid & 63;
    const size_t base = (size_t)blockIdx.x * (size_t)COLS;
    const float4* __restrict__ xin  = (const float4*)(x + base);
    float4*       __restrict__ xout = (float4*)(out + base);

    const int k = __builtin_amdgcn_readfirstlane(kptr[0]);

    __shared__ unsigned twv[NWAVES];          // per-wave k-th thresholds
    __shared__ unsigned cand[NWAVES * KCAP];  // 4 KB candidate keys

    // Load 16 elems/thread (coalesced float4); keep only KEYS in registers —
    // floats are reconstructed bit-exactly in the epilogue (saves 16 VGPRs).
    unsigned key[EPT];
#pragma unroll
    for (int i = 0; i < F4PT; ++i) {
        const float4 v = xin[i * TPB + tid];
        key[i*4+0] = f2k(__float_as_uint(v.x));
        key[i*4+1] = f2k(__float_as_uint(v.y));
        key[i*4+2] = f2k(__float_as_uint(v.z));
        key[i*4+3] = f2k(__float_as_uint(v.w));
    }

    // ---- Phase 1: wave-local EXACT k-th-largest key of this wave's 1024
    // elements. 2-way bisection, 32 rounds: pure ballot+s_bcnt1, counts
    // accumulate in SGPRs. No barriers, no shuffles, no LDS.
    // Invariant: count(key >= lo) >= k  AND  count(key >= hi) < k.
    uint64_t lo = 0, hi = 1ull << 32;
#pragma unroll 1
    for (int r = 0; r < 32; ++r) {
        const uint64_t mid = lo + ((hi - lo) >> 1);
        const unsigned t = (unsigned)mid;
        unsigned c = 0;
#pragma unroll
        for (int e = 0; e < EPT; ++e)
            c += sbcnt(__builtin_amdgcn_ballot_w64(key[e] >= t));
        if ((int)c >= k) lo = mid; else hi = mid;
    }
    if (lane == 0) twv[wid] = (unsigned)lo;
    __syncthreads();                                   // barrier 1 of 2

    // ---- t* = max over the 16 wave thresholds.
    // Proof: row threshold T satisfies T >= t_w for every wave w (if T < t_w
    // then count_w(>=T+1) >= count_w(>=t_w) >= k > count_row(>=T+1), contra),
    // hence T >= t*. So every element with key > t* is a candidate, and
    // count_w(key > t*) <= count_w(>= t_w + 1) < k per wave.
    unsigned tv = twv[lane & (NWAVES - 1)];
    { unsigned o = __shfl_xor(tv, 1); tv = tv > o ? tv : o; }
    { unsigned o = __shfl_xor(tv, 2); tv = tv > o ? tv : o; }
    { unsigned o = __shfl_xor(tv, 4); tv = tv > o ? tv : o; }
    { unsigned o = __shfl_xor(tv, 8); tv = tv > o ? tv : o; }
    const unsigned tstar = (unsigned)__builtin_amdgcn_readfirstlane((int)tv);

    // ---- Per-wave candidate compaction into k slots:
    //   slots [0, cb):       all keys strictly > t*   (cb < k guaranteed)
    //   slots [cb, cb+meq):  copies of t* (capped at k total)
    //   remaining slots:     0 (never affects thresholds >= 1)
    // This cap rule is exact under duplicates (keeping "first k candidates in
    // scan order" instead would be WRONG — it can drop a key > t*).
    const unsigned wbase = (unsigned)wid * (unsigned)k;
    unsigned cb = 0;
#pragma unroll
    for (int e = 0; e < EPT; ++e) {
        const unsigned long long mb = __builtin_amdgcn_ballot_w64(key[e] > tstar);
        if (key[e] > tstar) cand[wbase + cb + rank_lt(mb)] = key[e];
        cb += sbcnt(mb);
    }
    unsigned meq = 0;
#pragma unroll
    for (int e = 0; e < EPT; ++e)
        meq += sbcnt(__builtin_amdgcn_ballot_w64(key[e] == tstar));
    for (unsigned j = (unsigned)lane; j < (unsigned)k; j += 64)
        if (j >= cb) cand[wbase + j] = ((j - cb) < meq) ? tstar : 0u;
    __syncthreads();                                   // barrier 2 of 2

    // ---- Phase 2: every wave redundantly selects the k-th largest of the
    // <=1024 candidate keys (deterministic: identical data+path per wave, so
    // no further sync needed). Interval [t*, max+1) — typically ~24 rounds.
    const int total = NWAVES * k;
    unsigned ck[16];
#pragma unroll
    for (int j = 0; j < 16; ++j) {
        const int idx = j * 64 + lane;
        ck[j] = (idx < total) ? cand[idx] : 0u;
    }
    unsigned wmax = 0;
#pragma unroll
    for (int j = 0; j < 16; ++j) wmax = wmax > ck[j] ? wmax : ck[j];
    { unsigned o = __shfl_xor(wmax,  1); wmax = wmax > o ? wmax : o; }
    { unsigned o = __shfl_xor(wmax,  2); wmax = wmax > o ? wmax : o; }
    { unsigned o = __shfl_xor(wmax,  4); wmax = wmax > o ? wmax : o; }
    { unsigned o = __shfl_xor(wmax,  8); wmax = wmax > o ? wmax : o; }
    { unsigned o = __shfl_xor(wmax, 16); wmax = wmax > o ? wmax : o; }
    { unsigned o = __shfl_xor(wmax, 32); wmax = wmax > o ? wmax : o; }

    uint64_t lo2 = tstar;
    uint64_t hi2 = (uint64_t)(unsigned)__builtin_amdgcn_readfirstlane((int)wmax) + 1;
#pragma unroll 1
    while (hi2 - lo2 > 1) {
        const uint64_t mid = lo2 + ((hi2 - lo2) >> 1);
        const unsigned t = (unsigned)mid;
        unsigned c = 0;
#pragma unroll
        for (int j = 0; j < 16; ++j)
            c += sbcnt(__builtin_amdgcn_ballot_w64(ck[j] >= t));
        if ((int)c >= k) lo2 = mid; else hi2 = mid;
    }

    // lo2 is exactly the k-th largest key of the row (ties handled: output
    // uses >= threshold, matching jnp.where(x >= thresh)).
    const unsigned tk = (unsigned)lo2;
#pragma unroll
    for (int i = 0; i < F4PT; ++i) {
        float4 o;
        const unsigned k0 = key[i*4+0], k1 = key[i*4+1];
        const unsigned k2 = key[i*4+2], k3 = key[i*4+3];
        o.x = (k0 >= tk) ? __uint_as_float(k2f_bits(k0)) : 0.0f;
        o.y = (k1 >= tk) ? __uint_as_float(k2f_bits(k1)) : 0.0f;
        o.z = (k2 >= tk) ? __uint_as_float(k2f_bits(k2)) : 0.0f;
        o.w = (k3 >= tk) ? __uint_as_float(k2f_bits(k3)) : 0.0f;
        xout[i * TPB + tid] = o;
    }
}

extern "C" void kernel_launch(void* const* d_in, const int* in_sizes, int n_in,
                              void* d_out, int out_size, void* d_ws, size_t ws_size,
                              hipStream_t stream) {
    const float* x  = (const float*)d_in[0];
    const int*   kp = (const int*)d_in[1];
    float*       o  = (float*)d_out;
    const int rows = in_sizes[0] / COLS;
    topk_row_kernel<<<rows, TPB, 0, stream>>>(x, kp, o);
}

// Round 6
// 1018.437 us; speedup vs baseline: 1.1779x; 1.1779x over previous
//
#include <hip/hip_runtime.h>
#include <stdint.h>

#define COLS 16384
#define TPB 1024
#define NWAVES 16               // 16 waves per block (one block per row)
#define EPT 16                  // elements per thread
#define F4PT 4                  // float4 per thread
#define KCAP 64                 // supports k <= 64 (harness: k == 64)

// Order-preserving float -> u32 key map (monotone bijection over non-NaN).
__device__ __forceinline__ unsigned f2k(unsigned u) {
    return (u & 0x80000000u) ? ~u : (u | 0x80000000u);
}
// Exact inverse of f2k (bit-exact float reconstruction).
__device__ __forceinline__ unsigned k2f_bits(unsigned key) {
    return (key & 0x80000000u) ? (key ^ 0x80000000u) : ~key;
}
// Scalar popcount (cold compaction path only — SALU pressure fine there).
__device__ __forceinline__ unsigned sbcnt(unsigned long long m) {
    unsigned c;
    asm("s_bcnt1_i32_b64 %0, %1" : "=s"(c) : "s"(m) : "scc");
    return c;
}
// Rank of this lane among set bits below it (v_mbcnt pair, VALU).
__device__ __forceinline__ unsigned rank_lt(unsigned long long m) {
    unsigned r = __builtin_amdgcn_mbcnt_lo((unsigned)m, 0u);
    return __builtin_amdgcn_mbcnt_hi((unsigned)(m >> 32), r);
}
// Wave-wide uniform count of (key >= t) across all 64 lanes x N regs.
// Pure intrinsics: per-lane v_cmp+v_addc accumulate (4 independent chains,
// all VALU) + 6-step shfl_xor tree. Replaces the R1 s_bcnt1 scheme that
// oversubscribed the CU-shared scalar unit ~5x (1 SALU per 4 SIMDs), and
// the R2/R3 v_bcnt inline-asm that corrupted registers (absmax=468).
template <int N>
__device__ __forceinline__ int wave_count_ge(const unsigned (&key)[N], unsigned t) {
    int c0 = 0, c1 = 0, c2 = 0, c3 = 0;
#pragma unroll
    for (int e = 0; e < N; e += 4) {
        c0 += (key[e+0] >= t);
        c1 += (key[e+1] >= t);
        c2 += (key[e+2] >= t);
        c3 += (key[e+3] >= t);
    }
    int c = (c0 + c1) + (c2 + c3);
    c += __shfl_xor(c, 1);
    c += __shfl_xor(c, 2);
    c += __shfl_xor(c, 4);
    c += __shfl_xor(c, 8);
    c += __shfl_xor(c, 16);
    c += __shfl_xor(c, 32);
    return __builtin_amdgcn_readfirstlane(c);
}

__global__ __launch_bounds__(TPB, 8) void topk_row_kernel(
        const float* __restrict__ x,
        const int* __restrict__ kptr,
        float* __restrict__ out) {
    const int tid  = threadIdx.x;
    const int wid  = tid >> 6;
    const int lane = tid & 63;
    const size_t base = (size_t)blockIdx.x * (size_t)COLS;
    const float4* __restrict__ xin  = (const float4*)(x + base);
    float4*       __restrict__ xout = (float4*)(out + base);

    const int k = __builtin_amdgcn_readfirstlane(kptr[0]);

    __shared__ unsigned twv[NWAVES];          // per-wave phase-1 thresholds
    __shared__ unsigned cand[NWAVES * KCAP];  // 4 KB candidate keys (padded)

    // Load 16 elems/thread (coalesced float4); keep only KEYS in registers.
    unsigned key[EPT];
#pragma unroll
    for (int i = 0; i < F4PT; ++i) {
        const float4 v = xin[i * TPB + tid];
        key[i*4+0] = f2k(__float_as_uint(v.x));
        key[i*4+1] = f2k(__float_as_uint(v.y));
        key[i*4+2] = f2k(__float_as_uint(v.z));
        key[i*4+3] = f2k(__float_as_uint(v.w));
    }

    // ---- Phase 1: wave-local k-th-largest key of this wave's 1024 elems.
    // Midpoint bisection, trip count hard-capped at 32 (hi-lo halves every
    // round from 2^32, so the cap is exact, never binding early).
    // Invariant: count(>=lo) >= k AND count(>=hi) < k.
    // EARLY EXIT when count == k exactly: {key >= lo} is then a valid
    // top-k set for this wave (count(>lo) <= k, which the compaction's
    // capacity bound tolerates). Tie-straddle cases never hit count==k and
    // run to convergence, yielding the exact k-th key.
    uint64_t lo = 0, hi = 1ull << 32;
#pragma unroll 1
    for (int r = 0; r < 32; ++r) {
        if (hi - lo <= 1) break;
        const uint64_t mid = lo + ((hi - lo) >> 1);
        const int c = wave_count_ge(key, (unsigned)mid);
        if (c >= k) {
            lo = mid;
            if (c == k) break;
        } else {
            hi = mid;
        }
    }
    if (lane == 0) twv[wid] = (unsigned)lo;
    __syncthreads();                                   // barrier 1 of 2

    // ---- t* = max over the 16 wave thresholds.
    // Row threshold T >= t_w for every wave w (if T < t_w then
    // count_w(>=T+1) >= count_w(>=t_w) >= k > count_row(>=T+1), contra),
    // hence T >= t*. Every element with key > t* is a candidate, and
    // count_w(key > t*) <= count_w(>= t_w) <= k per wave (== k possible
    // only via the early exit; capacity below is exactly k slots/wave).
    unsigned tv = twv[lane & (NWAVES - 1)];
    { unsigned o = (unsigned)__shfl_xor((int)tv, 1); tv = tv > o ? tv : o; }
    { unsigned o = (unsigned)__shfl_xor((int)tv, 2); tv = tv > o ? tv : o; }
    { unsigned o = (unsigned)__shfl_xor((int)tv, 4); tv = tv > o ? tv : o; }
    { unsigned o = (unsigned)__shfl_xor((int)tv, 8); tv = tv > o ? tv : o; }
    const unsigned tstar = (unsigned)__builtin_amdgcn_readfirstlane((int)tv);

    // ---- Per-wave candidate compaction into k slots:
    //   slots [0, cb):       all keys strictly > t*   (cb <= k guaranteed)
    //   slots [cb, cb+meq):  copies of t* (capped at k total; none if cb==k)
    //   remaining slots:     0 (harmless: phase-2 probes are > t* >= 0)
    // Exact under duplicates. Cold path: sbcnt SALU pressure is fine.
    const unsigned wbase = (unsigned)wid * (unsigned)k;
    unsigned cb = 0;
#pragma unroll
    for (int e = 0; e < EPT; ++e) {
        const unsigned long long mb = __builtin_amdgcn_ballot_w64(key[e] > tstar);
        if (key[e] > tstar) cand[wbase + cb + rank_lt(mb)] = key[e];
        cb += sbcnt(mb);
    }
    unsigned meq = 0;
#pragma unroll
    for (int e = 0; e < EPT; ++e)
        meq += sbcnt(__builtin_amdgcn_ballot_w64(key[e] == tstar));
    for (unsigned j = (unsigned)lane; j < (unsigned)k; j += 64)
        if (j >= cb) cand[wbase + j] = ((j - cb) < meq) ? tstar : 0u;
    __syncthreads();                                   // barrier 2 of 2

    // ---- Phase 2: every wave redundantly selects the k-th largest of the
    // <=1024 candidate keys (deterministic: identical data+path per wave,
    // no further sync). Interval (t*, wmax]; ~8-12 rounds typical.
    const int total = NWAVES * k;
    unsigned ck[16];
#pragma unroll
    for (int j = 0; j < 16; ++j) {
        const int idx = j * 64 + lane;
        ck[j] = (idx < total) ? cand[idx] : 0u;
    }
    unsigned wm = 0;
#pragma unroll
    for (int j = 0; j < 16; ++j) wm = wm > ck[j] ? wm : ck[j];
    { unsigned o = (unsigned)__shfl_xor((int)wm,  1); wm = wm > o ? wm : o; }
    { unsigned o = (unsigned)__shfl_xor((int)wm,  2); wm = wm > o ? wm : o; }
    { unsigned o = (unsigned)__shfl_xor((int)wm,  4); wm = wm > o ? wm : o; }
    { unsigned o = (unsigned)__shfl_xor((int)wm,  8); wm = wm > o ? wm : o; }
    { unsigned o = (unsigned)__shfl_xor((int)wm, 16); wm = wm > o ? wm : o; }
    { unsigned o = (unsigned)__shfl_xor((int)wm, 32); wm = wm > o ? wm : o; }

    uint64_t lo2 = tstar;
    uint64_t hi2 = (uint64_t)(unsigned)__builtin_amdgcn_readfirstlane((int)wm) + 1;
#pragma unroll 1
    for (int r = 0; r < 32; ++r) {
        if (hi2 - lo2 <= 1) break;
        const uint64_t mid = lo2 + ((hi2 - lo2) >> 1);
        const int c = wave_count_ge(ck, (unsigned)mid);
        if (c >= k) {
            lo2 = mid;
            if (c == k) break;
        } else {
            hi2 = mid;
        }
    }

    // lo2 is a valid row threshold: {key >= lo2} equals the reference
    // top-k kept set (ties included), so outputs match bit-exactly.
    const unsigned tk = (unsigned)lo2;
#pragma unroll
    for (int i = 0; i < F4PT; ++i) {
        float4 o;
        const unsigned k0 = key[i*4+0], k1 = key[i*4+1];
        const unsigned k2 = key[i*4+2], k3 = key[i*4+3];
        o.x = (k0 >= tk) ? __uint_as_float(k2f_bits(k0)) : 0.0f;
        o.y = (k1 >= tk) ? __uint_as_float(k2f_bits(k1)) : 0.0f;
        o.z = (k2 >= tk) ? __uint_as_float(k2f_bits(k2)) : 0.0f;
        o.w = (k3 >= tk) ? __uint_as_float(k2f_bits(k3)) : 0.0f;
        xout[i * TPB + tid] = o;
    }
}

extern "C" void kernel_launch(void* const* d_in, const int* in_sizes, int n_in,
                              void* d_out, int out_size, void* d_ws, size_t ws_size,
                              hipStream_t stream) {
    const float* x  = (const float*)d_in[0];
    const int*   kp = (const int*)d_in[1];
    float*       o  = (float*)d_out;
    const int rows = in_sizes[0] / COLS;
    topk_row_kernel<<<rows, TPB, 0, stream>>>(x, kp, o);
}